// Round 11
// baseline (136.853 us; speedup 1.0000x reference)
//
#include <hip/hip_runtime.h>
#include <math.h>

#define H 512
#define W 512
#define IMG (H*W)
#define NIMG 32           // 16 images from y_hat + 16 from y
#define NSTRIP 10         // 56-col output strips per row
#define SW 56
#define RB 16             // output rows per band
#define NBAND 32          // 32*16 = 512 exactly

typedef unsigned long long u64;

__device__ __forceinline__ int reflect_idx(int i, int n) {
    if (i < 0) i = -i;
    if (i >= n) i = 2 * n - 2 - i;
    return i;
}

__device__ __forceinline__ float bperm_f(int addr, float v) {
    return __int_as_float(__builtin_amdgcn_ds_bpermute(addr, __float_as_int(v)));
}

// Composed 7-tap kernels: blur(5-tap gaussian) composed with sobel [1,2,1]/[-1,0,1].
#define S0 0.05448868454964294f
#define S1 0.35317871110251920f
#define S2 0.94551131545035710f
#define S3 1.29364257779496160f
#define A1 0.05448868454964294f
#define A2 0.24420134200323332f
#define A3 0.34813126234460456f

// ---------------------------------------------------------------------------
// Kernel 1 (line-scan, row-PAIR pipelined): one wave per (image,strip,band).
// Lane = gray col 56s-4+lane. Each iteration: consume 2 prefetched rows,
// prefetch next 2, 2 h-rows via 12 bpermutes, 2 mag rows, 2 NMS rows, one
// 16B paired store. 10240 waves = 40/CU (oversubscribed vs 32-wave cap).
// Output: 56-bit words, plane[img][strip][row].
// ---------------------------------------------------------------------------
__global__ __launch_bounds__(256, 5) void k_edges(const float* __restrict__ yhat,
                                                  const float* __restrict__ yy,
                                                  u64* __restrict__ strongP,
                                                  u64* __restrict__ weakP) {
    const int wid = blockIdx.x * 4 + (threadIdx.x >> 6);
    const int lane = threadIdx.x & 63;
    const int n = wid / (NSTRIP * NBAND);
    const int rem = wid - n * (NSTRIP * NBAND);
    const int s = rem / NBAND;
    const int band = rem - s * NBAND;
    const int y0 = band * RB;
    const float* src = (n < 16) ? (yhat + (size_t)n * 3 * IMG)
                                : (yy + (size_t)(n - 16) * 3 * IMG);

    const int c = s * SW - 4 + lane;
    const int cx = reflect_idx(c, W);
    const bool colok = ((unsigned)c < (unsigned)W);
    const u64 omask = (s == 9) ? 0xFFull : 0x00FFFFFFFFFFFFFFull;

    const int aM3 = ((lane - 3) << 2), aM2 = ((lane - 2) << 2), aM1 = ((lane - 1) << 2);
    const int aP1 = ((lane + 1) << 2), aP2 = ((lane + 2) << 2), aP3 = ((lane + 3) << 2);

    float hx[7], hy[7];
#pragma unroll
    for (int j = 0; j < 7; j++) { hx[j] = 0.f; hy[j] = 0.f; }

    const u64 outBase = ((size_t)n * NSTRIP + s) * H;

    // prefetched pair registers
    float r0, g0c, b0, r1, g1c, b1;
    {
        const float* p0 = src + (size_t)reflect_idx(y0 - 4, H) * W + cx;
        const float* p1 = src + (size_t)reflect_idx(y0 - 3, H) * W + cx;
        r0 = p0[0]; g0c = p0[IMG]; b0 = p0[2 * IMG];
        r1 = p1[0]; g1c = p1[IMG]; b1 = p1[2 * IMG];
    }

#define PREFETCH(k)                                                             \
    {                                                                           \
        const float* p0 = src + (size_t)reflect_idx(y0 - 4 + 2 * (k), H) * W + cx; \
        const float* p1 = src + (size_t)reflect_idx(y0 - 3 + 2 * (k), H) * W + cx; \
        r0 = p0[0]; g0c = p0[IMG]; b0 = p0[2 * IMG];                            \
        r1 = p1[0]; g1c = p1[IMG]; b1 = p1[2 * IMG];                            \
    }

#define HPUSH(gv)                                                               \
    {                                                                           \
        float gm1 = bperm_f(aM1, gv), gp1 = bperm_f(aP1, gv);                   \
        float gm2 = bperm_f(aM2, gv), gp2 = bperm_f(aP2, gv);                   \
        float gm3 = bperm_f(aM3, gv), gp3 = bperm_f(aP3, gv);                   \
        _Pragma("unroll")                                                       \
        for (int j = 0; j < 6; j++) { hx[j] = hx[j + 1]; hy[j] = hy[j + 1]; }   \
        hx[6] = A3 * (gp1 - gm1) + A2 * (gp2 - gm2) + A1 * (gp3 - gm3);         \
        hy[6] = S3 * gv + S2 * (gp1 + gm1) + S1 * (gp2 + gm2) + S0 * (gp3 + gm3); \
    }

    // MAG computes mag^2 + L/R + dir for FIFO-center row `mr`
#define MAG(mr, mv, mvL, mvR, dv)                                               \
    {                                                                           \
        float gx = S3 * hx[3] + S2 * (hx[4] + hx[2])                            \
                 + S1 * (hx[5] + hx[1]) + S0 * (hx[6] + hx[0]);                 \
        float gy = A3 * (hy[4] - hy[2]) + A2 * (hy[5] - hy[1])                  \
                 + A1 * (hy[6] - hy[0]);                                        \
        bool okm = colok && ((unsigned)(mr) < (unsigned)H);                     \
        mv = okm ? (gx * gx + gy * gy + 1e-12f) : 0.f;                          \
        mvL = bperm_f(aM1, mv);                                                 \
        mvR = bperm_f(aP1, mv);                                                 \
        float ax = fabsf(gx), ay = fabsf(gy);                                   \
        dv = (ay <= 0.4142135623730951f * ax) ? 0                               \
           : (ay >= 2.414213562373095f * ax) ? 2                                \
           : (((gx > 0.f) == (gy > 0.f)) ? 1 : 3);                              \
    }

    // ---- prime: pairs 0..2 fill FIFO (gray rows y0-4 .. y0+1) ----
#pragma unroll
    for (int k = 0; k < 3; k++) {
        float ga = 0.299f * r0 + 0.587f * g0c + 0.114f * b0;
        float gb = 0.299f * r1 + 0.587f * g1c + 0.114f * b1;
        PREFETCH(k + 1);
        HPUSH(ga);
        HPUSH(gb);
    }

    // pair 3: gray rows y0+2,y0+3 -> mag rows y0-1, y0
    float mm1, mm1L, mm1R, m0, m0L, m0R;
    int dir0;
    {
        float ga = 0.299f * r0 + 0.587f * g0c + 0.114f * b0;
        float gb = 0.299f * r1 + 0.587f * g1c + 0.114f * b1;
        PREFETCH(4);
        int dtmp;
        HPUSH(ga);
        MAG(y0 - 1, mm1, mm1L, mm1R, dtmp);
        (void)dtmp;
        HPUSH(gb);
        MAG(y0, m0, m0L, m0R, dir0);
    }

    // ---- steady: pairs k=4..4+RB/2-1; outputs rows t0=y0+2k-8, t1=t0+1 ----
#pragma unroll 4
    for (int k = 4; k < 4 + RB / 2; k++) {
        float ga = 0.299f * r0 + 0.587f * g0c + 0.114f * b0;
        float gb = 0.299f * r1 + 0.587f * g1c + 0.114f * b1;
        if (k < 4 + RB / 2 - 1) PREFETCH(k + 1);

        float ma, maL, maR, mb, mbL, mbR;
        int da, db;
        HPUSH(ga);
        MAG(y0 + 2 * k - 7, ma, maL, maR, da);
        HPUSH(gb);
        MAG(y0 + 2 * k - 6, mb, mbL, mbR, db);

        // row t0: mags (mm1, m0, ma), dir0
        float n1 = (dir0 == 0) ? m0R : (dir0 == 1) ? maR : (dir0 == 2) ? ma : maL;
        float n2 = (dir0 == 0) ? m0L : (dir0 == 1) ? mm1L : (dir0 == 2) ? mm1 : mm1R;
        bool ok0 = (m0 >= n1) && (m0 >= n2);
        u64 bs0 = __ballot(ok0 && (m0 >= 0.04f));
        u64 bw0 = __ballot(ok0 && (m0 >= 0.01f));

        // row t1: mags (m0, ma, mb), dir = da
        float n3 = (da == 0) ? maR : (da == 1) ? mbR : (da == 2) ? mb : mbL;
        float n4 = (da == 0) ? maL : (da == 1) ? m0L : (da == 2) ? m0 : m0R;
        bool ok1 = (ma >= n3) && (ma >= n4);
        u64 bs1 = __ballot(ok1 && (ma >= 0.04f));
        u64 bw1 = __ballot(ok1 && (ma >= 0.01f));

        if (lane == 0) {
            int t0 = y0 + 2 * k - 8;
            ulonglong2 vs, vw;
            vs.x = (bs0 >> 4) & omask; vs.y = (bs1 >> 4) & omask;
            vw.x = (bw0 >> 4) & omask; vw.y = (bw1 >> 4) & omask;
            *(ulonglong2*)&strongP[outBase + t0] = vs;
            *(ulonglong2*)&weakP[outBase + t0] = vw;
        }

        mm1 = ma; mm1L = maL; mm1R = maR;
        m0 = mb; m0L = mbL; m0R = mbR;
        dir0 = db;
    }
#undef PREFETCH
#undef HPUSH
#undef MAG
}

// ---------------------------------------------------------------------------
// Kernel 2: bit-parallel hysteresis (10 iters, exact via light cone) + diff
// count. One wave per 32x32 tile per image-pair; lane l = row ty0-10+l.
// Loads from 56-bit strip words via 3-word funnel shift.
// ---------------------------------------------------------------------------
__device__ __forceinline__ u64 ldw10(const u64* p, int img, int y, int q, bool ok) {
    return (ok && q >= 0 && q < NSTRIP) ? p[((size_t)img * NSTRIP + q) * H + y] : 0ULL;
}

__global__ __launch_bounds__(256) void k_hyst(const u64* __restrict__ strongP,
                                              const u64* __restrict__ weakP,
                                              unsigned int* __restrict__ partials) {
    __shared__ unsigned int part[4];
    const int wy = threadIdx.x >> 6;
    const int wave = blockIdx.x * 4 + wy;
    const int lane = threadIdx.x & 63;
    const int tile = wave & 255;
    const int pair = wave >> 8;          // 0..15
    const int tx0 = (tile & 15) * 32;
    const int ty0 = (tile >> 4) * 32;

    const int y = ty0 - 10 + lane;
    const bool rowok = (lane < 52) && (y >= 0) && (y < H);
    const int yc = rowok ? y : 0;

    const int x = tx0 - 10;
    const int q0 = (x < 0) ? -1 : (x / 56);
    const int r = x - 56 * q0;           // 1..55, never 0
    const int sh1 = 56 - r;
    const bool need3 = (r > 48);
    const int sh2 = 112 - r;

    const int imgA = pair, imgB = pair + 16;
    u64 sA, wA, sB, wB;
    {
        u64 w0, w1, w2;
        w0 = ldw10(strongP, imgA, yc, q0, rowok);
        w1 = ldw10(strongP, imgA, yc, q0 + 1, rowok);
        w2 = need3 ? ldw10(strongP, imgA, yc, q0 + 2, rowok) : 0ULL;
        sA = (w0 >> r) | (w1 << sh1) | (need3 ? (w2 << sh2) : 0ULL);
        w0 = ldw10(weakP, imgA, yc, q0, rowok);
        w1 = ldw10(weakP, imgA, yc, q0 + 1, rowok);
        w2 = need3 ? ldw10(weakP, imgA, yc, q0 + 2, rowok) : 0ULL;
        wA = (w0 >> r) | (w1 << sh1) | (need3 ? (w2 << sh2) : 0ULL);
        w0 = ldw10(strongP, imgB, yc, q0, rowok);
        w1 = ldw10(strongP, imgB, yc, q0 + 1, rowok);
        w2 = need3 ? ldw10(strongP, imgB, yc, q0 + 2, rowok) : 0ULL;
        sB = (w0 >> r) | (w1 << sh1) | (need3 ? (w2 << sh2) : 0ULL);
        w0 = ldw10(weakP, imgB, yc, q0, rowok);
        w1 = ldw10(weakP, imgB, yc, q0 + 1, rowok);
        w2 = need3 ? ldw10(weakP, imgB, yc, q0 + 2, rowok) : 0ULL;
        wB = (w0 >> r) | (w1 << sh1) | (need3 ? (w2 << sh2) : 0ULL);
    }

#pragma unroll
    for (int it = 0; it < 10; it++) {
        u64 up = __shfl_up(sA, 1), dn = __shfl_down(sA, 1);
        u64 t = up | sA | dn;
        sA |= (t | (t << 1) | (t >> 1)) & wA;
        up = __shfl_up(sB, 1); dn = __shfl_down(sB, 1);
        t = up | sB | dn;
        sB |= (t | (t << 1) | (t >> 1)) & wB;
    }

    unsigned int cgt = 0;
    if (lane >= 10 && lane < 42) {
        const u64 mask = ((1ULL << 42) - (1ULL << 10));
        cgt = (unsigned int)__popcll((sA ^ sB) & mask);
    }
#pragma unroll
    for (int off = 32; off > 0; off >>= 1) cgt += __shfl_down(cgt, off);
    if (lane == 0) part[wy] = cgt;
    __syncthreads();
    if (threadIdx.x == 0)
        partials[blockIdx.x] = part[0] + part[1] + part[2] + part[3];
}

// ---------------------------------------------------------------------------
// Kernel 3: sum 1024 partials, scale, write scalar. One block.
// ---------------------------------------------------------------------------
__global__ __launch_bounds__(256) void k_final(const unsigned int* __restrict__ partials,
                                               float* __restrict__ out) {
    __shared__ unsigned int part[4];
    unsigned int c = 0;
    for (int i = threadIdx.x; i < 1024; i += 256) c += partials[i];
#pragma unroll
    for (int off = 32; off > 0; off >>= 1) c += __shfl_down(c, off);
    const int lane = threadIdx.x & 63;
    const int wy = threadIdx.x >> 6;
    if (lane == 0) part[wy] = c;
    __syncthreads();
    if (threadIdx.x == 0)
        out[0] = (float)(part[0] + part[1] + part[2] + part[3]) * (1.0f / 4194304.0f);
}

extern "C" void kernel_launch(void* const* d_in, const int* in_sizes, int n_in,
                              void* d_out, int out_size, void* d_ws, size_t ws_size,
                              hipStream_t stream) {
    const float* yhat = (const float*)d_in[0];
    const float* yy = (const float*)d_in[1];

    u64* strongP = (u64*)d_ws;                        // 32*10*512 u64 = 1.31 MB
    u64* weakP = strongP + (size_t)NIMG * NSTRIP * H; // 1.31 MB
    unsigned int* partials = (unsigned int*)(weakP + (size_t)NIMG * NSTRIP * H);

    // 32 img x 10 strips x 32 bands = 10240 waves, 4 waves/block
    k_edges<<<2560, 256, 0, stream>>>(yhat, yy, strongP, weakP);

    // 256 tiles x 16 pairs = 4096 waves, 4 waves/block
    k_hyst<<<1024, 256, 0, stream>>>(strongP, weakP, partials);
    k_final<<<1, 256, 0, stream>>>(partials, (float*)d_out);
}